// Round 11
// baseline (524.102 us; speedup 1.0000x reference)
//
#include <hip/hip_runtime.h>
#include <hip/hip_bf16.h>

typedef __hip_bfloat16 bf16;
typedef __attribute__((ext_vector_type(8))) short s8v;
typedef __attribute__((ext_vector_type(4))) float f4v;

#define NTOT 32768   // 32*32*32 spatial positions
#define HSZ ((size_t)NTOT*16)   // elements per head slice

__device__ __forceinline__ float bflo(unsigned int u){ union{unsigned int i;float f;}v; v.i=u<<16; return v.f; }
__device__ __forceinline__ float bfhi(unsigned int u){ union{unsigned int i;float f;}v; v.i=u&0xffff0000u; return v.f; }
__device__ __forceinline__ unsigned short f2bu(float f){ bf16 h = __float2bfloat16(f); unsigned short s; __builtin_memcpy(&s,&h,2); return s; }
__device__ __forceinline__ unsigned int pk2(float a, float b){ return (unsigned int)f2bu(a) | ((unsigned int)f2bu(b)<<16); }

__device__ __forceinline__ void load8(const bf16* p, float* o){
  uint4 u = *(const uint4*)p;
  o[0]=bflo(u.x); o[1]=bfhi(u.x); o[2]=bflo(u.y); o[3]=bfhi(u.y);
  o[4]=bflo(u.z); o[5]=bfhi(u.z); o[6]=bflo(u.w); o[7]=bfhi(u.w);
}
__device__ __forceinline__ void load16(const bf16* p, float* o){
  const uint4* q = (const uint4*)p;
  uint4 u0 = q[0], u1 = q[1];
  o[0]=bflo(u0.x); o[1]=bfhi(u0.x); o[2]=bflo(u0.y); o[3]=bfhi(u0.y);
  o[4]=bflo(u0.z); o[5]=bfhi(u0.z); o[6]=bflo(u0.w); o[7]=bfhi(u0.w);
  o[8]=bflo(u1.x); o[9]=bfhi(u1.x); o[10]=bflo(u1.y); o[11]=bfhi(u1.y);
  o[12]=bflo(u1.z); o[13]=bfhi(u1.z); o[14]=bflo(u1.w); o[15]=bfhi(u1.w);
}
__device__ __forceinline__ void store16(bf16* p, const float* v){
  uint4 u0, u1;
  u0.x=pk2(v[0],v[1]); u0.y=pk2(v[2],v[3]); u0.z=pk2(v[4],v[5]); u0.w=pk2(v[6],v[7]);
  u1.x=pk2(v[8],v[9]); u1.y=pk2(v[10],v[11]); u1.z=pk2(v[12],v[13]); u1.w=pk2(v[14],v[15]);
  uint4* q=(uint4*)p; q[0]=u0; q[1]=u1;
}

// ---------------- fused LayerNorm + qkvv GEMM (MFMA) ----------------
__global__ __launch_bounds__(256) void k_qkvv(const float* __restrict__ x,
    const float* __restrict__ lng, const float* __restrict__ lnb,
    const float* __restrict__ w,
    bf16* __restrict__ Qh, bf16* __restrict__ Kh, bf16* __restrict__ Vsh, bf16* __restrict__ Vch)
{
  __shared__ unsigned char sm[64000];
  float* xt = (float*)sm;                       // [64c][66] fp32
  float* mean_s = (float*)(sm + 16896);
  float* rstd_s = (float*)(sm + 16896 + 256);
  float* g_s    = (float*)(sm + 16896 + 512);
  float* b_s    = (float*)(sm + 16896 + 768);
  unsigned char* A2 = sm + 17920;               // [64p][144B] bf16
  unsigned char* Wb = sm + 27136;               // [256j][144B] bf16
  unsigned char* Cout = sm;                     // phase2: [64p][528B] bf16

  int t = threadIdx.x;
  int n0 = blockIdx.x * 64;
  #pragma unroll
  for (int i=0;i<4;i++){
    int idx = t + i*256; int c = idx>>4, g = idx&15;
    *(float4*)&xt[c*66 + g*4] = *(const float4*)(x + (size_t)c*NTOT + n0 + g*4);
  }
  #pragma unroll
  for (int i=0;i<8;i++){
    int idx = t + i*256; int j = idx>>3, g = idx&7;
    float4 wa = *(const float4*)(w + (size_t)j*64 + g*8);
    float4 wb = *(const float4*)(w + (size_t)j*64 + g*8 + 4);
    uint4 u; u.x=pk2(wa.x,wa.y); u.y=pk2(wa.z,wa.w); u.z=pk2(wb.x,wb.y); u.w=pk2(wb.z,wb.w);
    *(uint4*)(Wb + j*144 + g*16) = u;
  }
  if (t<64){ g_s[t]=lng[t]; b_s[t]=lnb[t]; }
  __syncthreads();
  if (t<64){
    float s=0.f, ss=0.f;
    for (int c=0;c<64;c++){ float v=xt[c*66+t]; s+=v; ss+=v*v; }
    float m = s*(1.f/64.f);
    float var = ss*(1.f/64.f) - m*m;
    mean_s[t]=m; rstd_s[t]=rsqrtf(var+1e-5f);
  }
  __syncthreads();
  {
    int p = t>>2, c0 = (t&3)*16;
    float m = mean_s[p], rs = rstd_s[p];
    unsigned short tmp[16];
    #pragma unroll
    for (int i=0;i<16;i++){
      int c = c0+i;
      tmp[i] = f2bu((xt[c*66+p]-m)*rs*g_s[c] + b_s[c]);
    }
    *(uint4*)(A2 + p*144 + c0*2)      = *(uint4*)&tmp[0];
    *(uint4*)(A2 + p*144 + c0*2 + 16) = *(uint4*)&tmp[8];
  }
  __syncthreads();
  int wv = t>>6, lane = t&63, r = lane&15, q = lane>>4;
  f4v acc[4][4];
  #pragma unroll
  for (int mt=0;mt<4;mt++)
    #pragma unroll
    for (int nt=0;nt<4;nt++){ acc[mt][nt][0]=0.f; acc[mt][nt][1]=0.f; acc[mt][nt][2]=0.f; acc[mt][nt][3]=0.f; }
  #pragma unroll
  for (int ks=0; ks<2; ++ks){
    s8v af[4], bfr[4];
    #pragma unroll
    for (int mt=0;mt<4;mt++) af[mt] = *(const s8v*)(A2 + (mt*16+r)*144 + ks*64 + q*16);
    #pragma unroll
    for (int nt=0;nt<4;nt++) bfr[nt] = *(const s8v*)(Wb + ((wv*4+nt)*16+r)*144 + ks*64 + q*16);
    #pragma unroll
    for (int mt=0;mt<4;mt++)
      #pragma unroll
      for (int nt=0;nt<4;nt++)
        acc[mt][nt] = __builtin_amdgcn_mfma_f32_16x16x32_bf16(af[mt], bfr[nt], acc[mt][nt], 0, 0, 0);
  }
  __syncthreads();
  #pragma unroll
  for (int mt=0;mt<4;mt++)
    #pragma unroll
    for (int nt=0;nt<4;nt++){
      int j = (wv*4+nt)*16 + r;
      #pragma unroll
      for (int reg=0;reg<4;reg++){
        int p = mt*16 + q*4 + reg;
        *(unsigned short*)(Cout + p*528 + j*2) = f2bu(acc[mt][nt][reg]);
      }
    }
  __syncthreads();
  bf16* bases[4] = {Qh, Kh, Vch, Vsh};   // j-order: q | k | v_ca | v_sa
  #pragma unroll
  for (int k=0;k<4;k++){
    int chunk = t + k*256;
    int combo = chunk >> 6, pos = chunk & 63;
    int tensor = combo >> 2, h = combo & 3;
    uint4 v = *(const uint4*)(Cout + pos*528 + (tensor*64 + h*16)*2);
    *(uint4*)((unsigned char*)bases[tensor] + ((size_t)h*HSZ + (size_t)(n0+pos)*16)*2) = v;
  }
}

// ---------------- channel attention: partial Gram + norms ----------------
__global__ __launch_bounds__(256) void k_chanpart(const bf16* __restrict__ Qh, const bf16* __restrict__ Kh,
    float* __restrict__ G, float* __restrict__ NQ, float* __restrict__ NK)
{
  int h = blockIdx.y;
  int t = threadIdx.x; int d = t>>4, e = t&15;
  __shared__ float qs[128][16];
  __shared__ float ks[128][16];
  float acc=0.f, accq=0.f, acck=0.f;
  for (int stage=0; stage<4; ++stage){
    int n0 = blockIdx.x*512 + stage*128;
    __syncthreads();
    {
      int row = t & 127, which = t >> 7;
      const bf16* p = (which ? Kh : Qh) + ((size_t)h*NTOT + n0 + row)*16;
      float tmp[16]; load16(p, tmp);
      float* dst = which ? &ks[row][0] : &qs[row][0];
      #pragma unroll
      for (int i=0;i<16;i++) dst[i]=tmp[i];
    }
    __syncthreads();
    for (int i=0;i<128;i++){
      float qv = qs[i][d], kv = ks[i][e];
      acc += qv*kv;
      if (e==0) accq += qv*qv;
      if (e==1){ float kd = ks[i][d]; acck += kd*kd; }
    }
  }
  atomicAdd(&G[(h*16+d)*16+e], acc);
  if (e==0) atomicAdd(&NQ[h*16+d], accq);
  if (e==1) atomicAdd(&NK[h*16+d], acck);
}

// ---------------- spatial window attention + channel apply (fused chanfin) ----------------
__global__ __launch_bounds__(256) void k_spatial(const bf16* __restrict__ Qh, const bf16* __restrict__ Kh,
    const bf16* __restrict__ Vsh, const bf16* __restrict__ Vch,
    const float* __restrict__ G, const float* __restrict__ NQ, const float* __restrict__ NK,
    const float* __restrict__ temp, const float* __restrict__ temp2,
    const float* __restrict__ rpb, const float* __restrict__ qemb,
    bf16* __restrict__ xsa, bf16* __restrict__ xca)
{
  __shared__ float aca_s[1024];
  __shared__ float rpb_s[108];
  __shared__ float qemb_s[64];
  int t = threadIdx.x;
  if (t < 64){
    int hh = t>>4;
    float tp = temp[hh];
    float nq = fmaxf(sqrtf(NQ[t]), 1e-12f);
    float sv[16]; float mx=-3.0e38f;
    #pragma unroll
    for (int e=0;e<16;e++){
      float nk = fmaxf(sqrtf(NK[hh*16+e]), 1e-12f);
      sv[e] = G[t*16+e] / (nq*nk) * tp;
      mx = fmaxf(mx, sv[e]);
    }
    float sum=0.f;
    #pragma unroll
    for (int e=0;e<16;e++){ sv[e]=expf(sv[e]-mx); sum+=sv[e]; }
    float inv = 1.f/sum;
    #pragma unroll
    for (int e=0;e<16;e++) aca_s[t*16+e] = sv[e]*inv;
  }
  if (t<108) rpb_s[t]=rpb[t];
  if (t<64) qemb_s[t]=qemb[t];
  __syncthreads();
  int lane = t & 63, h = t >> 6;
  int n = blockIdx.x*64 + lane;
  int a = n>>10, b=(n>>5)&31, c=n&31;
  const bf16* Kb = Kh + (size_t)h*HSZ;
  const bf16* Vb = Vsh + (size_t)h*HSZ;
  float q[16]; load16(Qh + (size_t)h*HSZ + (size_t)n*16, q);
  float s2=0.f;
  #pragma unroll
  for (int d=0;d<16;d++) s2 += q[d]*q[d];
  float inv = 1.f/fmaxf(sqrtf(s2), 1e-12f);
  float st2 = log1pf(expf(temp2[h]));
  #pragma unroll
  for (int d=0;d<16;d++) q[d] = (q[d]*inv + qemb_s[h*16+d])*st2;
  float sc[27]; float mx = -3.0e38f;
  #pragma unroll
  for (int kk=0;kk<27;kk++){
    int da=kk/9-1, db=(kk/3)%3-1, dc=kk%3-1;
    int aa=a+da, bb=b+db, cc=c+dc;
    float s = -3.0e38f;
    if ((unsigned)aa<32u && (unsigned)bb<32u && (unsigned)cc<32u){
      int nn = n + da*1024 + db*32 + dc;
      float kv[16]; load16(Kb + (size_t)nn*16, kv);
      s = rpb_s[h*27+kk];
      #pragma unroll
      for (int d=0;d<16;d++) s += q[d]*kv[d];
    }
    sc[kk]=s; mx = fmaxf(mx, s);
  }
  float sum=0.f;
  #pragma unroll
  for (int kk=0;kk<27;kk++){ float e = expf(sc[kk]-mx); sc[kk]=e; sum+=e; }
  float invs = 1.f/sum;
  float o[16];
  #pragma unroll
  for (int d=0;d<16;d++) o[d]=0.f;
  #pragma unroll
  for (int kk=0;kk<27;kk++){
    int da=kk/9-1, db=(kk/3)%3-1, dc=kk%3-1;
    int aa=a+da, bb=b+db, cc=c+dc;
    if ((unsigned)aa<32u && (unsigned)bb<32u && (unsigned)cc<32u){
      int nn = n + da*1024 + db*32 + dc;
      float vv[16]; load16(Vb + (size_t)nn*16, vv);
      float p = sc[kk];
      #pragma unroll
      for (int d=0;d<16;d++) o[d] += p*vv[d];
    }
  }
  #pragma unroll
  for (int d=0;d<16;d++) o[d]*=invs;
  store16(xsa + ((size_t)h*NTOT + n)*16, o);
  float vca[16]; load16(Vch + (size_t)h*HSZ + (size_t)n*16, vca);
  float oc[16];
  #pragma unroll
  for (int d=0;d<16;d++){
    float s=0.f;
    #pragma unroll
    for (int e=0;e<16;e++) s += aca_s[(h*16+d)*16+e]*vca[e];
    oc[d]=s;
  }
  store16(xca + (size_t)n*64 + h*16, oc);
}

// ---------------- projections + gamma residual -> skip' [n][64] fp32 ----------------
__global__ __launch_bounds__(256) void k_epilogue(const float* __restrict__ x,
    const bf16* __restrict__ xsa, const bf16* __restrict__ xca,
    const float* __restrict__ op1w, const float* __restrict__ op1b,
    const float* __restrict__ op2w, const float* __restrict__ op2b,
    const float* __restrict__ gamma, float* __restrict__ skipf)
{
  __shared__ float xs_s[64][68];
  __shared__ float xc_s[64][68];
  __shared__ float trans[64][68];
  int t = threadIdx.x;
  int n0 = blockIdx.x * 64;
  #pragma unroll
  for (int it=0; it<2; ++it){
    int idx = t + it*256;
    int p = idx >> 3, cg = idx & 7;
    float a8[8], c8[8];
    load8(xsa + (size_t)(n0+p)*64 + cg*8, a8);
    load8(xca + (size_t)(n0+p)*64 + cg*8, c8);
    #pragma unroll
    for (int i=0;i<8;i++){ xs_s[p][cg*8+i]=a8[i]; xc_s[p][cg*8+i]=c8[i]; }
  }
  int co = t & 63, pg = t >> 6;
  const float* wrow = (co < 32) ? (op1w + (size_t)co*64) : (op2w + (size_t)(co-32)*64);
  float wreg[64];
  #pragma unroll
  for (int i=0;i<16;i++) *(float4*)&wreg[i*4] = *(const float4*)(wrow + i*4);
  float bv = (co<32) ? op1b[co] : op2b[co-32];
  float gv = gamma[co];
  __syncthreads();
  const float* xt = (co<32) ? &xs_s[0][0] : &xc_s[0][0];
  float out16[16];
  #pragma unroll
  for (int i=0;i<16;i++){
    int p = pg*16 + i;
    const float* xr = xt + p*68;
    float s = bv;
    #pragma unroll
    for (int k4=0;k4<16;k4++){
      float4 xv = *(const float4*)(xr + k4*4);
      s += wreg[k4*4]*xv.x + wreg[k4*4+1]*xv.y + wreg[k4*4+2]*xv.z + wreg[k4*4+3]*xv.w;
    }
    out16[i] = s;
  }
  size_t base = (size_t)co*NTOT + n0 + pg*16;
  #pragma unroll
  for (int i4=0;i4<4;i4++){
    float4 xv = *(const float4*)(x + base + i4*4);
    out16[i4*4]   = xv.x + gv*out16[i4*4];
    out16[i4*4+1] = xv.y + gv*out16[i4*4+1];
    out16[i4*4+2] = xv.z + gv*out16[i4*4+2];
    out16[i4*4+3] = xv.w + gv*out16[i4*4+3];
  }
  #pragma unroll
  for (int i=0;i<16;i++) trans[pg*16+i][co] = out16[i];
  __syncthreads();
  {
    int pos = t >> 2, grp = t & 3;
    float* dst = skipf + (size_t)(n0+pos)*64 + grp*16;
    #pragma unroll
    for (int i4=0;i4<4;i4++)
      *(float4*)(dst + i4*4) = *(const float4*)&trans[pos][grp*16 + i4*4];
  }
}

// ---------------- conv weight prep (+ stat zeroing) ----------------
__global__ void k_wprep(const float* __restrict__ wA, const float* __restrict__ wB_,
    const float* __restrict__ wC, const float* __restrict__ wD,
    const float* __restrict__ w8, bf16* __restrict__ WB, float* __restrict__ w8t,
    float* __restrict__ statz)
{
  int idx = blockIdx.x*256 + threadIdx.x;
  if (idx < 1152) statz[idx] = 0.f;                       // G/NQ/NK
  if (idx >= 1664 && idx < 1668) statz[idx] = 0.f;        // conv last-block counters
  if (idx < 458752){
    int j = idx & 7;
    int rr = (idx>>3) & 15;
    int q = (idx>>7) & 3;
    int nt = (idx>>9) & 3;
    int rest = idx >> 11;
    int tp = rest % 14;
    int rest2 = rest / 14;
    int cc = rest2 & 3;
    int conv = rest2 >> 2;
    int co = nt*16 + rr;
    int tap = 2*tp + (q>>1);
    int ci = cc*16 + (q&1)*8 + j;
    const float* src = conv==0?wA:conv==1?wB_:conv==2?wC:wD;
    float v = (tap < 27) ? src[((size_t)co*64 + ci)*27 + tap] : 0.f;
    WB[idx] = __float2bfloat16(v);
  }
  if (idx < 4096){ int ci = idx>>6, co = idx&63; w8t[ci*64+co] = w8[(size_t)co*64+ci]; }
}

// ---------------- MFMA implicit-GEMM 3x3x3 conv, direct [n][64] src, fused BN/pad/res + last-block BN reduce ----------------
// MODE0: src fp32 [n][64], no BN.  MODE1: src bf16 + BN+LReLU.  MODE2: + fp32 residual.
template<int MODE>
__global__ __launch_bounds__(256, 2) void k_conv3x(const void* __restrict__ src,
    const float* __restrict__ stats, const float* __restrict__ g, const float* __restrict__ be,
    const float* __restrict__ resid,
    const bf16* __restrict__ WB, const float* __restrict__ bias,
    bf16* __restrict__ Yout, float* __restrict__ BNpart,
    float* __restrict__ BNout, unsigned int* __restrict__ ctr)
{
  __shared__ float smf[17408];
  unsigned char* smb = (unsigned char*)smf;
  int t = threadIdx.x;
  int w = t >> 6, lane = t & 63;
  int r = lane & 15, q = lane >> 4;
  int qe = q & 1, qh = q >> 1;
  int a = blockIdx.x >> 4, b0 = (blockIdx.x & 15) * 2;
  int hh = t & 7;

  float m8[8], rs8[8], be8[8];
  if (MODE != 0){
    #pragma unroll
    for (int i=0;i<8;i++){
      int ci = hh*8 + i;
      float S = stats[ci*2], SS = stats[ci*2+1];
      float m = S*(1.f/NTOT);
      m8[i] = m;
      rs8[i] = rsqrtf(SS*(1.f/NTOT) - m*m + 1e-5f) * g[ci];
      be8[i] = be[ci];
    }
  }

  // ---- staging: 408 slab rows x 128B, zero borders, BN/res inline ----
  if (MODE == 0){
    #pragma unroll
    for (int c0=0;c0<2;++c0){
      int kb = c0*7, kn = (c0==0)?7:6;
      float4 f0[7], f1[7]; int fl[7];
      #pragma unroll
      for (int k=0;k<7;k++){
        fl[k]=0;
        if (k<kn){
          int idx = t + (kb+k)*256;
          if (idx < 3264){
            int pos = idx>>3;
            int par=pos/136, rem=pos-par*136, pbr=rem/34, pc=rem-pbr*34;
            int pa=a+par, pb=b0+pbr;
            fl[k]=1;
            if (pa>=1&&pa<=32&&pb>=1&&pb<=32&&pc>=1&&pc<=32){
              int nsrc=(pa-1)*1024+(pb-1)*32+(pc-1);
              const float* p = (const float*)src + (size_t)nsrc*64 + hh*8;
              f0[k]=*(const float4*)p; f1[k]=*(const float4*)(p+4);
              fl[k]=2;
            }
          }
        }
      }
      #pragma unroll
      for (int k=0;k<7;k++){
        if (k<kn && fl[k]){
          int pos = (t + (kb+k)*256)>>3;
          uint4 o={0,0,0,0};
          if (fl[k]==2){
            o.x=pk2(f0[k].x,f0[k].y); o.y=pk2(f0[k].z,f0[k].w);
            o.z=pk2(f1[k].x,f1[k].y); o.w=pk2(f1[k].z,f1[k].w);
          }
          *(uint4*)(smb + pos*144 + hh*16) = o;
        }
      }
    }
  } else {
    const int CS = (MODE==2)?5:13;
    const int NC = (MODE==2)?3:1;
    #pragma unroll
    for (int c0=0;c0<NC;++c0){
      int kb = c0*CS;
      int kn = (MODE==2) ? ((c0==2)?3:5) : 13;
      uint4 u[CS]; float4 r0[CS], r1[CS]; int fl[CS];
      #pragma unroll
      for (int k=0;k<CS;k++){
        fl[k]=0;
        if (k<kn){
          int idx = t + (kb+k)*256;
          if (idx < 3264){
            int pos = idx>>3;
            int par=pos/136, rem=pos-par*136, pbr=rem/34, pc=rem-pbr*34;
            int pa=a+par, pb=b0+pbr;
            fl[k]=1;
            if (pa>=1&&pa<=32&&pb>=1&&pb<=32&&pc>=1&&pc<=32){
              int nsrc=(pa-1)*1024+(pb-1)*32+(pc-1);
              u[k] = *(const uint4*)((const unsigned char*)src + ((size_t)nsrc*64 + hh*8)*2);
              if (MODE==2){
                const float* rp = resid + (size_t)nsrc*64 + hh*8;
                r0[k]=*(const float4*)rp; r1[k]=*(const float4*)(rp+4);
              }
              fl[k]=2;
            }
          }
        }
      }
      #pragma unroll
      for (int k=0;k<CS;k++){
        if (k<kn && fl[k]){
          int pos = (t + (kb+k)*256)>>3;
          uint4 o={0,0,0,0};
          if (fl[k]==2){
            float v[8];
            v[0]=bflo(u[k].x); v[1]=bfhi(u[k].x); v[2]=bflo(u[k].y); v[3]=bfhi(u[k].y);
            v[4]=bflo(u[k].z); v[5]=bfhi(u[k].z); v[6]=bflo(u[k].w); v[7]=bfhi(u[k].w);
            float rv[8];
            if (MODE==2){
              rv[0]=r0[k].x; rv[1]=r0[k].y; rv[2]=r0[k].z; rv[3]=r0[k].w;
              rv[4]=r1[k].x; rv[5]=r1[k].y; rv[6]=r1[k].z; rv[7]=r1[k].w;
            }
            #pragma unroll
            for (int i=0;i<8;i++){
              float y = (v[i]-m8[i])*rs8[i] + be8[i];
              if (MODE==2) y += rv[i];
              v[i] = y>0.f ? y : 0.01f*y;
            }
            o.x=pk2(v[0],v[1]); o.y=pk2(v[2],v[3]); o.z=pk2(v[4],v[5]); o.w=pk2(v[6],v[7]);
          }
          *(uint4*)(smb + pos*144 + hh*16) = o;
        }
      }
    }
  }

  int toff[14];
  #pragma unroll
  for (int tp=0;tp<14;++tp){
    int tap = 2*tp + qh;
    int da = tap/9, rem = tap - da*9, db = rem/3, dc = rem - db*3;
    toff[tp] = (tap<27) ? (((da*4+db)*34 + dc)*144) : 0;
  }
  int F[4];
  #pragma unroll
  for (int mt=0;mt<4;mt++) F[mt] = (((mt>>1)*34 + (mt&1)*16 + r)*144) + w*32 + qe*16;
  const unsigned char* wbp = (const unsigned char*)WB + (size_t)w*57344 + lane*16;

  f4v acc[4][4];
  #pragma unroll
  for (int mt=0;mt<4;mt++)
    #pragma unroll
    for (int nt=0;nt<4;nt++){ acc[mt][nt][0]=0.f; acc[mt][nt][1]=0.f; acc[mt][nt][2]=0.f; acc[mt][nt][3]=0.f; }

  __syncthreads();

  s8v aC[4], bC[4], bN[4];
  #pragma unroll
  for (int mt=0;mt<4;mt++) aC[mt] = *(const s8v*)(smb + F[mt] + toff[0]);
  #pragma unroll
  for (int nt=0;nt<4;nt++){ bC[nt] = *(const s8v*)(wbp + nt*1024); bN[nt] = *(const s8v*)(wbp + 4096 + nt*1024); }

  #pragma unroll
  for (int tp=0; tp<14; ++tp){
    s8v aN[4], bN2[4];
    if (tp < 12){
      #pragma unroll
      for (int nt=0;nt<4;nt++) bN2[nt] = *(const s8v*)(wbp + (tp+2)*4096 + nt*1024);
    }
    if (tp < 13){
      #pragma unroll
      for (int mt=0;mt<4;mt++) aN[mt] = *(const s8v*)(smb + F[mt] + toff[tp+1]);
    }
    #pragma unroll
    for (int mt=0;mt<4;mt++)
      #pragma unroll
      for (int nt=0;nt<4;nt++)
        acc[mt][nt] = __builtin_amdgcn_mfma_f32_16x16x32_bf16(aC[mt], bC[nt], acc[mt][nt], 0, 0, 0);
    #pragma unroll
    for (int nt=0;nt<4;nt++) bC[nt] = bN[nt];
    if (tp < 12){
      #pragma unroll
      for (int nt=0;nt<4;nt++) bN[nt] = bN2[nt];
    }
    if (tp < 13){
      #pragma unroll
      for (int mt=0;mt<4;mt++) aC[mt] = aN[mt];
    }
  }

  __syncthreads();
  #pragma unroll
  for (int mt=0;mt<4;mt++)
    #pragma unroll
    for (int nt=0;nt<4;nt++)
      *(float4*)&smf[w*4352 + (nt*16+r)*68 + mt*16 + q*4] = *(float4*)&acc[mt][nt];
  __syncthreads();

  float vals[16];
  {
    int co = t >> 2, pg = t & 3;
    float bv = bias[co];
    #pragma unroll
    for (int i4=0;i4<4;i4++){
      int p = pg*16 + i4*4;
      float4 s0 = *(const float4*)&smf[0*4352 + co*68 + p];
      float4 s1 = *(const float4*)&smf[1*4352 + co*68 + p];
      float4 s2 = *(const float4*)&smf[2*4352 + co*68 + p];
      float4 s3 = *(const float4*)&smf[3*4352 + co*68 + p];
      vals[i4*4+0] = s0.x+s1.x+s2.x+s3.x+bv;
      vals[i4*4+1] = s0.y+s1.y+s2.y+s3.y+bv;
      vals[i4*4+2] = s0.z+s1.z+s2.z+s3.z+bv;
      vals[i4*4+3] = s0.w+s1.w+s2.w+s3.w+bv;
    }
    float s=0.f, ss=0.f;
    #pragma unroll
    for (int i=0;i<16;i++){ s+=vals[i]; ss+=vals[i]*vals[i]; }
    s += __shfl_xor(s,1); ss += __shfl_xor(ss,1);
    s += __shfl_xor(s,2); ss += __shfl_xor(ss,2);
    if (pg==0){
      BNpart[(size_t)blockIdx.x*128 + co*2]     = s;
      BNpart[(size_t)blockIdx.x*128 + co*2 + 1] = ss;
    }
  }
  __syncthreads();
  {
    int co = t >> 2, pg = t & 3;
    #pragma unroll
    for (int i=0;i<16;i++) smf[(pg*16+i)*68 + co] = vals[i];
  }
  __syncthreads();
  {
    int pos = t >> 2, grp = t & 3;
    float v16[16];
    #pragma unroll
    for (int i4=0;i4<4;i4++) *(float4*)&v16[i4*4] = *(const float4*)&smf[pos*68 + grp*16 + i4*4];
    uint4 u0, u1;
    u0.x=pk2(v16[0],v16[1]); u0.y=pk2(v16[2],v16[3]); u0.z=pk2(v16[4],v16[5]); u0.w=pk2(v16[6],v16[7]);
    u1.x=pk2(v16[8],v16[9]); u1.y=pk2(v16[10],v16[11]); u1.z=pk2(v16[12],v16[13]); u1.w=pk2(v16[14],v16[15]);
    int nb = a*1024 + (b0 + (pos>>5))*32 + (pos&31);
    uint4* dst = (uint4*)((unsigned char*)Yout + ((size_t)nb*64 + grp*16)*2);
    dst[0] = u0; dst[1] = u1;
  }
  // ---- last-block consolidation of BN partials ----
  __threadfence();
  __syncthreads();
  unsigned int* flag = (unsigned int*)smf;
  if (t == 0) flag[0] = (atomicAdd(ctr, 1u) == 511u) ? 1u : 0u;
  __syncthreads();
  if (flag[0]){
    int col = t & 127, half = t >> 7;
    float acc2 = 0.f;
    #pragma unroll 8
    for (int rr2 = half*256; rr2 < half*256+256; ++rr2) acc2 += BNpart[rr2*128 + col];
    float* red = smf + 64;
    red[half*128 + col] = acc2;
    __syncthreads();
    if (t < 128) BNout[t] = red[t] + red[128 + t];
  }
}

// ---------------- fused BN+res chain + 1x1x1 conv + final residual -> fp32 out ----------------
__global__ __launch_bounds__(256) void k_conv1f(const bf16* __restrict__ Y4,
    const float* __restrict__ BN4, const float* __restrict__ g4, const float* __restrict__ be4,
    const bf16* __restrict__ Y2, const float* __restrict__ BN2,
    const float* __restrict__ g2, const float* __restrict__ be2,
    const float* __restrict__ skipf, const float* __restrict__ w8t, const float* __restrict__ b8,
    float* __restrict__ out)
{
  __shared__ float R2[64][68];   // [ci][n]
  __shared__ float skT[64][68];  // [co][n]
  __shared__ float wt[4096];
  __shared__ float bs[64];
  int t = threadIdx.x;
  int n0 = blockIdx.x * 64;
  #pragma unroll
  for (int k=0;k<4;k++){
    int idx = t + k*256;
    *(float4*)&wt[idx*4] = *(const float4*)(w8t + idx*4);
  }
  if (t < 64) bs[t] = b8[t];
  {
    int pos = t >> 2, grp = t & 3;
    int n = n0 + pos;
    float y2[16], y4[16], sk[16];
    load16(Y2 + (size_t)n*64 + grp*16, y2);
    load16(Y4 + (size_t)n*64 + grp*16, y4);
    #pragma unroll
    for (int i4=0;i4<4;i4++) *(float4*)&sk[i4*4] = *(const float4*)(skipf + (size_t)n*64 + grp*16 + i4*4);
    #pragma unroll
    for (int i=0;i<16;i++){
      int ci = grp*16+i;
      float S2=BN2[ci*2], SS2=BN2[ci*2+1];
      float m2=S2*(1.f/NTOT);
      float r2v=rsqrtf(SS2*(1.f/NTOT)-m2*m2+1e-5f);
      float R = (y2[i]-m2)*r2v*g2[ci]+be2[ci] + sk[i];
      R = R>0.f ? R : 0.01f*R;
      float S4=BN4[ci*2], SS4=BN4[ci*2+1];
      float m4=S4*(1.f/NTOT);
      float r4v=rsqrtf(SS4*(1.f/NTOT)-m4*m4+1e-5f);
      float vy = (y4[i]-m4)*r4v*g4[ci]+be4[ci] + R;
      vy = vy>0.f ? vy : 0.01f*vy;
      R2[ci][pos] = vy;
      skT[ci][pos] = sk[i];
    }
  }
  __syncthreads();
  int lane = t & 63, cg = t >> 6;
  float acc[16];
  #pragma unroll
  for (int j=0;j<16;j++) acc[j]=0.f;
  for (int ci=0; ci<64; ci++){
    float rv = R2[ci][lane];
    const float* wr = &wt[ci*64 + cg*16];
    float4 wa = *(const float4*)(wr);
    float4 wb = *(const float4*)(wr+4);
    float4 wc = *(const float4*)(wr+8);
    float4 wd = *(const float4*)(wr+12);
    acc[0]+=rv*wa.x; acc[1]+=rv*wa.y; acc[2]+=rv*wa.z; acc[3]+=rv*wa.w;
    acc[4]+=rv*wb.x; acc[5]+=rv*wb.y; acc[6]+=rv*wb.z; acc[7]+=rv*wb.w;
    acc[8]+=rv*wc.x; acc[9]+=rv*wc.y; acc[10]+=rv*wc.z; acc[11]+=rv*wc.w;
    acc[12]+=rv*wd.x; acc[13]+=rv*wd.y; acc[14]+=rv*wd.z; acc[15]+=rv*wd.w;
  }
  #pragma unroll
  for (int j=0;j<16;j++){
    int co = cg*16+j;
    out[(size_t)co*NTOT + n0 + lane] = acc[j] + bs[co] + skT[co][lane];
  }
}

extern "C" void kernel_launch(void* const* d_in, const int* in_sizes, int n_in,
                              void* d_out, int out_size, void* d_ws, size_t ws_size,
                              hipStream_t stream) {
  (void)in_sizes; (void)n_in; (void)out_size; (void)ws_size;
  const float* x      = (const float*)d_in[0];
  const float* ln_g   = (const float*)d_in[1];
  const float* ln_b   = (const float*)d_in[2];
  const float* gamma  = (const float*)d_in[3];
  const float* qkvv_w = (const float*)d_in[4];
  const float* temp   = (const float*)d_in[5];
  const float* temp2  = (const float*)d_in[6];
  const float* rpb    = (const float*)d_in[7];
  const float* qemb   = (const float*)d_in[8];
  const float* op1w   = (const float*)d_in[9];
  const float* op1b   = (const float*)d_in[10];
  const float* op2w   = (const float*)d_in[11];
  const float* op2b   = (const float*)d_in[12];
  const float* c51_w1 = (const float*)d_in[13];
  const float* c51_b1 = (const float*)d_in[14];
  const float* c51_g1 = (const float*)d_in[15];
  const float* c51_be1= (const float*)d_in[16];
  const float* c51_w2 = (const float*)d_in[17];
  const float* c51_b2 = (const float*)d_in[18];
  const float* c51_g2 = (const float*)d_in[19];
  const float* c51_be2= (const float*)d_in[20];
  const float* c52_w1 = (const float*)d_in[21];
  const float* c52_b1 = (const float*)d_in[22];
  const float* c52_g1 = (const float*)d_in[23];
  const float* c52_be1= (const float*)d_in[24];
  const float* c52_w2 = (const float*)d_in[25];
  const float* c52_b2 = (const float*)d_in[26];
  const float* c52_g2 = (const float*)d_in[27];
  const float* c52_be2= (const float*)d_in[28];
  const float* c8_w   = (const float*)d_in[29];
  const float* c8_b   = (const float*)d_in[30];

  unsigned char* ws = (unsigned char*)d_ws;
  const size_t MB = 1u<<20;
  bf16*  Qh   = (bf16*)(ws + 0);                 // 4 MB [h][N][16]
  bf16*  Kh   = (bf16*)(ws + 4*MB);              // 4 MB
  bf16*  Vsh  = (bf16*)(ws + 8*MB);              // 4 MB
  bf16*  Vch  = (bf16*)(ws + 12*MB);             // 4 MB
  bf16*  xsa  = (bf16*)(ws + 16*MB);             // 4 MB
  bf16*  xca  = (bf16*)(ws + 20*MB);             // 4 MB
  float* skipf= (float*)(ws + 24*MB);            // 8 MB [n][64] fp32
  float* stat = (float*)(ws + 32*MB);
  float* G    = stat + 0;                        // 1024
  float* NQ   = stat + 1024;                     // 64
  float* NK   = stat + 1088;                     // 64
  float* BN1  = stat + 1152;                     // 128 each
  float* BN2  = stat + 1312;
  float* BN3  = stat + 1472;
  float* BN4  = stat + 1632;                     // note: BN4 range 1632..1759 overlaps ctr region? no: ctrs at 1664.. -> move ctrs
  unsigned int* ctrs = (unsigned int*)(stat + 1664);
  bf16*  WB   = (bf16*)(ws + 33*MB);             // 917504 B
  float* w8t  = (float*)(ws + 33*MB + 1048576);  // 16 KB
  float* BNpart = (float*)(ws + 35*MB);          // 256 KB
  bf16*  Y1   = (bf16*)(ws + 36*MB);             // 4 MB [n][64]
  bf16*  Y2   = (bf16*)(ws + 40*MB);             // 4 MB (persists to conv1f)
  bf16*  Y3   = (bf16*)(ws + 44*MB);             // 4 MB
  bf16*  Y4   = (bf16*)(ws + 48*MB);             // 4 MB -> peak 52 MB

  // NOTE: BN4 (stat+1632..1759) would overlap ctrs at stat+1664 — relocate BN4 higher.
  BN4 = stat + 1792;

  k_wprep<<<1792,256,0,stream>>>(c51_w1, c51_w2, c52_w1, c52_w2, c8_w, WB, w8t, stat);
  k_qkvv<<<512,256,0,stream>>>(x, ln_g, ln_b, qkvv_w, Qh, Kh, Vsh, Vch);
  k_chanpart<<<dim3(64,4),256,0,stream>>>(Qh, Kh, G, NQ, NK);
  k_spatial<<<512,256,0,stream>>>(Qh, Kh, Vsh, Vch, G, NQ, NK, temp, temp2, rpb, qemb, xsa, xca);
  k_epilogue<<<512,256,0,stream>>>(x, xsa, xca, op1w, op1b, op2w, op2b, gamma, skipf);
  // resblock 1
  k_conv3x<0><<<512,256,0,stream>>>(skipf, nullptr, nullptr, nullptr, nullptr, WB + 0*114688, c51_b1, Y1, BNpart, BN1, ctrs+0);
  k_conv3x<1><<<512,256,0,stream>>>(Y1, BN1, c51_g1, c51_be1, nullptr, WB + 1*114688, c51_b2, Y2, BNpart, BN2, ctrs+1);
  // resblock 2 (staging computes R = lrelu(bn2(Y2)+skip))
  k_conv3x<2><<<512,256,0,stream>>>(Y2, BN2, c51_g2, c51_be2, skipf, WB + 2*114688, c52_b1, Y3, BNpart, BN3, ctrs+2);
  k_conv3x<1><<<512,256,0,stream>>>(Y3, BN3, c52_g1, c52_be1, nullptr, WB + 3*114688, c52_b2, Y4, BNpart, BN4, ctrs+3);
  // final: y = lrelu(bn4(Y4) + R), out = skip + conv1x1(y)
  k_conv1f<<<512,256,0,stream>>>(Y4, BN4, c52_g2, c52_be2, Y2, BN2, c51_g2, c51_be2, skipf, w8t, c8_b, (float*)d_out);
}

// Round 12
// 287.390 us; speedup vs baseline: 1.8237x; 1.8237x over previous
//
#include <hip/hip_runtime.h>
#include <hip/hip_bf16.h>

typedef __hip_bfloat16 bf16;
typedef __attribute__((ext_vector_type(8))) short s8v;
typedef __attribute__((ext_vector_type(4))) float f4v;

#define NTOT 32768   // 32*32*32 spatial positions
#define HSZ ((size_t)NTOT*16)   // elements per head slice

__device__ __forceinline__ float bflo(unsigned int u){ union{unsigned int i;float f;}v; v.i=u<<16; return v.f; }
__device__ __forceinline__ float bfhi(unsigned int u){ union{unsigned int i;float f;}v; v.i=u&0xffff0000u; return v.f; }
__device__ __forceinline__ unsigned short f2bu(float f){ bf16 h = __float2bfloat16(f); unsigned short s; __builtin_memcpy(&s,&h,2); return s; }
__device__ __forceinline__ unsigned int pk2(float a, float b){ return (unsigned int)f2bu(a) | ((unsigned int)f2bu(b)<<16); }

__device__ __forceinline__ void load16(const bf16* p, float* o){
  const uint4* q = (const uint4*)p;
  uint4 u0 = q[0], u1 = q[1];
  o[0]=bflo(u0.x); o[1]=bfhi(u0.x); o[2]=bflo(u0.y); o[3]=bfhi(u0.y);
  o[4]=bflo(u0.z); o[5]=bfhi(u0.z); o[6]=bflo(u0.w); o[7]=bfhi(u0.w);
  o[8]=bflo(u1.x); o[9]=bfhi(u1.x); o[10]=bflo(u1.y); o[11]=bfhi(u1.y);
  o[12]=bflo(u1.z); o[13]=bfhi(u1.z); o[14]=bflo(u1.w); o[15]=bfhi(u1.w);
}

// ---------------- fused LayerNorm + qkvv GEMM (MFMA) ----------------
__global__ __launch_bounds__(256) void k_qkvv(const float* __restrict__ x,
    const float* __restrict__ lng, const float* __restrict__ lnb,
    const float* __restrict__ w,
    bf16* __restrict__ Qh, bf16* __restrict__ Kh, bf16* __restrict__ Vsh, bf16* __restrict__ Vch)
{
  __shared__ unsigned char sm[64000];
  float* xt = (float*)sm;                       // [64c][66] fp32
  float* mean_s = (float*)(sm + 16896);
  float* rstd_s = (float*)(sm + 16896 + 256);
  float* g_s    = (float*)(sm + 16896 + 512);
  float* b_s    = (float*)(sm + 16896 + 768);
  unsigned char* A2 = sm + 17920;               // [64p][144B] bf16
  unsigned char* Wb = sm + 27136;               // [256j][144B] bf16
  unsigned char* Cout = sm;                     // phase2: [64p][528B] bf16

  int t = threadIdx.x;
  int n0 = blockIdx.x * 64;
  #pragma unroll
  for (int i=0;i<4;i++){
    int idx = t + i*256; int c = idx>>4, g = idx&15;
    *(float4*)&xt[c*66 + g*4] = *(const float4*)(x + (size_t)c*NTOT + n0 + g*4);
  }
  #pragma unroll
  for (int i=0;i<8;i++){
    int idx = t + i*256; int j = idx>>3, g = idx&7;
    float4 wa = *(const float4*)(w + (size_t)j*64 + g*8);
    float4 wb = *(const float4*)(w + (size_t)j*64 + g*8 + 4);
    uint4 u; u.x=pk2(wa.x,wa.y); u.y=pk2(wa.z,wa.w); u.z=pk2(wb.x,wb.y); u.w=pk2(wb.z,wb.w);
    *(uint4*)(Wb + j*144 + g*16) = u;
  }
  if (t<64){ g_s[t]=lng[t]; b_s[t]=lnb[t]; }
  __syncthreads();
  if (t<64){
    float s=0.f, ss=0.f;
    for (int c=0;c<64;c++){ float v=xt[c*66+t]; s+=v; ss+=v*v; }
    float m = s*(1.f/64.f);
    float var = ss*(1.f/64.f) - m*m;
    mean_s[t]=m; rstd_s[t]=rsqrtf(var+1e-5f);
  }
  __syncthreads();
  {
    int p = t>>2, c0 = (t&3)*16;
    float m = mean_s[p], rs = rstd_s[p];
    unsigned short tmp[16];
    #pragma unroll
    for (int i=0;i<16;i++){
      int c = c0+i;
      tmp[i] = f2bu((xt[c*66+p]-m)*rs*g_s[c] + b_s[c]);
    }
    *(uint4*)(A2 + p*144 + c0*2)      = *(uint4*)&tmp[0];
    *(uint4*)(A2 + p*144 + c0*2 + 16) = *(uint4*)&tmp[8];
  }
  __syncthreads();
  int wv = t>>6, lane = t&63, r = lane&15, q = lane>>4;
  f4v acc[4][4];
  #pragma unroll
  for (int mt=0;mt<4;mt++)
    #pragma unroll
    for (int nt=0;nt<4;nt++){ acc[mt][nt][0]=0.f; acc[mt][nt][1]=0.f; acc[mt][nt][2]=0.f; acc[mt][nt][3]=0.f; }
  #pragma unroll
  for (int ks=0; ks<2; ++ks){
    s8v af[4], bfr[4];
    #pragma unroll
    for (int mt=0;mt<4;mt++) af[mt] = *(const s8v*)(A2 + (mt*16+r)*144 + ks*64 + q*16);
    #pragma unroll
    for (int nt=0;nt<4;nt++) bfr[nt] = *(const s8v*)(Wb + ((wv*4+nt)*16+r)*144 + ks*64 + q*16);
    #pragma unroll
    for (int mt=0;mt<4;mt++)
      #pragma unroll
      for (int nt=0;nt<4;nt++)
        acc[mt][nt] = __builtin_amdgcn_mfma_f32_16x16x32_bf16(af[mt], bfr[nt], acc[mt][nt], 0, 0, 0);
  }
  __syncthreads();
  #pragma unroll
  for (int mt=0;mt<4;mt++)
    #pragma unroll
    for (int nt=0;nt<4;nt++){
      int j = (wv*4+nt)*16 + r;
      #pragma unroll
      for (int reg=0;reg<4;reg++){
        int p = mt*16 + q*4 + reg;
        *(unsigned short*)(Cout + p*528 + j*2) = f2bu(acc[mt][nt][reg]);
      }
    }
  __syncthreads();
  bf16* bases[4] = {Qh, Kh, Vch, Vsh};   // j-order: q | k | v_ca | v_sa
  #pragma unroll
  for (int k=0;k<4;k++){
    int chunk = t + k*256;
    int combo = chunk >> 6, pos = chunk & 63;
    int tensor = combo >> 2, h = combo & 3;
    uint4 v = *(const uint4*)(Cout + pos*528 + (tensor*64 + h*16)*2);
    *(uint4*)((unsigned char*)bases[tensor] + ((size_t)h*HSZ + (size_t)(n0+pos)*16)*2) = v;
  }
}

// ---------------- channel attention: partial Gram + norms ----------------
__global__ __launch_bounds__(256) void k_chanpart(const bf16* __restrict__ Qh, const bf16* __restrict__ Kh,
    float* __restrict__ G, float* __restrict__ NQ, float* __restrict__ NK)
{
  int h = blockIdx.y;
  int t = threadIdx.x; int d = t>>4, e = t&15;
  __shared__ float qs[128][16];
  __shared__ float ks[128][16];
  float acc=0.f, accq=0.f, acck=0.f;
  for (int stage=0; stage<4; ++stage){
    int n0 = blockIdx.x*512 + stage*128;
    __syncthreads();
    {
      int row = t & 127, which = t >> 7;
      const bf16* p = (which ? Kh : Qh) + ((size_t)h*NTOT + n0 + row)*16;
      float tmp[16]; load16(p, tmp);
      float* dst = which ? &ks[row][0] : &qs[row][0];
      #pragma unroll
      for (int i=0;i<16;i++) dst[i]=tmp[i];
    }
    __syncthreads();
    for (int i=0;i<128;i++){
      float qv = qs[i][d], kv = ks[i][e];
      acc += qv*kv;
      if (e==0) accq += qv*qv;
      if (e==1){ float kd = ks[i][d]; acck += kd*kd; }
    }
  }
  atomicAdd(&G[(h*16+d)*16+e], acc);
  if (e==0) atomicAdd(&NQ[h*16+d], accq);
  if (e==1) atomicAdd(&NK[h*16+d], acck);
}

// ---------------- spatial attention + channel apply + projections + residual -> skip' [m][64] fp32 ----------------
__global__ __launch_bounds__(256) void k_spatial(const bf16* __restrict__ Qh, const bf16* __restrict__ Kh,
    const bf16* __restrict__ Vsh, const bf16* __restrict__ Vch,
    const float* __restrict__ G, const float* __restrict__ NQ, const float* __restrict__ NK,
    const float* __restrict__ temp, const float* __restrict__ temp2,
    const float* __restrict__ rpb, const float* __restrict__ qemb,
    const float* __restrict__ x,
    const float* __restrict__ op1w, const float* __restrict__ op1b,
    const float* __restrict__ op2w, const float* __restrict__ op2b,
    const float* __restrict__ gamma, float* __restrict__ skipf)
{
  __shared__ float aca_s[1024];
  __shared__ float rpb_s[108];
  __shared__ float qemb_s[64];
  __shared__ float xs_s[64][68];   // SA, reshape-row-major: row = h*16 + (lane>>2), col = (lane&3)*16+d
  __shared__ float xc_s[64][68];   // CA, position-major:    row = lane,              col = h*16+d
  int t = threadIdx.x;
  int n0 = blockIdx.x * 64;
  if (t < 64){
    int hh = t>>4;
    float tp = temp[hh];
    float nq = fmaxf(sqrtf(NQ[t]), 1e-12f);
    float sv[16]; float mx=-3.0e38f;
    #pragma unroll
    for (int e=0;e<16;e++){
      float nk = fmaxf(sqrtf(NK[hh*16+e]), 1e-12f);
      sv[e] = G[t*16+e] / (nq*nk) * tp;
      mx = fmaxf(mx, sv[e]);
    }
    float sum=0.f;
    #pragma unroll
    for (int e=0;e<16;e++){ sv[e]=expf(sv[e]-mx); sum+=sv[e]; }
    float inv = 1.f/sum;
    #pragma unroll
    for (int e=0;e<16;e++) aca_s[t*16+e] = sv[e]*inv;
  }
  if (t<108) rpb_s[t]=rpb[t];
  if (t<64) qemb_s[t]=qemb[t];
  __syncthreads();
  int lane = t & 63, h = t >> 6;
  int n = n0 + lane;
  int a = n>>10, b=(n>>5)&31, c=n&31;
  const bf16* Kb = Kh + (size_t)h*HSZ;
  const bf16* Vb = Vsh + (size_t)h*HSZ;
  float q[16]; load16(Qh + (size_t)h*HSZ + (size_t)n*16, q);
  float s2=0.f;
  #pragma unroll
  for (int d=0;d<16;d++) s2 += q[d]*q[d];
  float inv = 1.f/fmaxf(sqrtf(s2), 1e-12f);
  float st2 = log1pf(expf(temp2[h]));
  #pragma unroll
  for (int d=0;d<16;d++) q[d] = (q[d]*inv + qemb_s[h*16+d])*st2;
  float sc[27]; float mx = -3.0e38f;
  #pragma unroll
  for (int kk=0;kk<27;kk++){
    int da=kk/9-1, db=(kk/3)%3-1, dc=kk%3-1;
    int aa=a+da, bb=b+db, cc=c+dc;
    float s = -3.0e38f;
    if ((unsigned)aa<32u && (unsigned)bb<32u && (unsigned)cc<32u){
      int nn = n + da*1024 + db*32 + dc;
      float kv[16]; load16(Kb + (size_t)nn*16, kv);
      s = rpb_s[h*27+kk];
      #pragma unroll
      for (int d=0;d<16;d++) s += q[d]*kv[d];
    }
    sc[kk]=s; mx = fmaxf(mx, s);
  }
  float sum=0.f;
  #pragma unroll
  for (int kk=0;kk<27;kk++){ float e = expf(sc[kk]-mx); sc[kk]=e; sum+=e; }
  float invs = 1.f/sum;
  float o[16];
  #pragma unroll
  for (int d=0;d<16;d++) o[d]=0.f;
  #pragma unroll
  for (int kk=0;kk<27;kk++){
    int da=kk/9-1, db=(kk/3)%3-1, dc=kk%3-1;
    int aa=a+da, bb=b+db, cc=c+dc;
    if ((unsigned)aa<32u && (unsigned)bb<32u && (unsigned)cc<32u){
      int nn = n + da*1024 + db*32 + dc;
      float vv[16]; load16(Vb + (size_t)nn*16, vv);
      float p = sc[kk];
      #pragma unroll
      for (int d=0;d<16;d++) o[d] += p*vv[d];
    }
  }
  {
    int jrow = h*16 + (lane>>2), cbase = (lane&3)*16;
    #pragma unroll
    for (int d=0;d<16;d++) xs_s[jrow][cbase + d] = o[d]*invs;
  }
  {
    float vca[16]; load16(Vch + (size_t)h*HSZ + (size_t)n*16, vca);
    #pragma unroll
    for (int d=0;d<16;d++){
      float s=0.f;
      #pragma unroll
      for (int e=0;e<16;e++) s += aca_s[(h*16+d)*16+e]*vca[e];
      xc_s[lane][h*16+d] = s;
    }
  }
  __syncthreads();
  // ---- projection + gamma residual ----
  int co = t & 63, pg = t >> 6;
  const float* wrow = (co < 32) ? (op1w + (size_t)co*64) : (op2w + (size_t)(co-32)*64);
  float wreg[64];
  #pragma unroll
  for (int i=0;i<16;i++) *(float4*)&wreg[i*4] = *(const float4*)(wrow + i*4);
  float bv = (co<32) ? op1b[co] : op2b[co-32];
  float gv = gamma[co];
  const float* xt_ = (co<32) ? &xs_s[0][0] : &xc_s[0][0];
  #pragma unroll
  for (int i=0;i<16;i++){
    int p = pg*16 + i;
    const float* xr = xt_ + p*68;
    float s = bv;
    #pragma unroll
    for (int k4=0;k4<16;k4++){
      float4 xv = *(const float4*)(xr + k4*4);
      s += wreg[k4*4]*xv.x + wreg[k4*4+1]*xv.y + wreg[k4*4+2]*xv.z + wreg[k4*4+3]*xv.w;
    }
    int m;
    if (co < 32){ int hh2 = p>>4, jj = p&15; m = hh2*8192 + (n0>>2) + jj; }
    else m = n0 + p;
    skipf[(size_t)m*64 + co] = x[(size_t)co*NTOT + m] + gv*s;
  }
}

// ---------------- conv weight prep (+ stat zeroing) ----------------
__global__ void k_wprep(const float* __restrict__ wA, const float* __restrict__ wB_,
    const float* __restrict__ wC, const float* __restrict__ wD,
    const float* __restrict__ w8, bf16* __restrict__ WB, float* __restrict__ w8t,
    float* __restrict__ statz)
{
  int idx = blockIdx.x*256 + threadIdx.x;
  if (idx < 1152) statz[idx] = 0.f;                       // G/NQ/NK
  if (idx < 458752){
    int j = idx & 7;
    int rr = (idx>>3) & 15;
    int q = (idx>>7) & 3;
    int nt = (idx>>9) & 3;
    int rest = idx >> 11;
    int tp = rest % 14;
    int rest2 = rest / 14;
    int cc = rest2 & 3;
    int conv = rest2 >> 2;
    int co = nt*16 + rr;
    int tap = 2*tp + (q>>1);
    int ci = cc*16 + (q&1)*8 + j;
    const float* src = conv==0?wA:conv==1?wB_:conv==2?wC:wD;
    float v = (tap < 27) ? src[((size_t)co*64 + ci)*27 + tap] : 0.f;
    WB[idx] = __float2bfloat16(v);
  }
  if (idx < 4096){ int ci = idx>>6, co = idx&63; w8t[ci*64+co] = w8[(size_t)co*64+ci]; }
}

// ---------------- MFMA implicit-GEMM 3x3x3 conv, direct [n][64] src, fused BN/pad/res ----------------
// MODE0: src fp32 [n][64], no BN.  MODE1: src bf16 + BN+LReLU.  MODE2: + fp32 residual.
template<int MODE>
__global__ __launch_bounds__(256, 2) void k_conv3x(const void* __restrict__ src,
    const float* __restrict__ stats, const float* __restrict__ g, const float* __restrict__ be,
    const float* __restrict__ resid,
    const bf16* __restrict__ WB, const float* __restrict__ bias,
    bf16* __restrict__ Yout, float* __restrict__ BNpart)
{
  __shared__ float smf[17408];
  unsigned char* smb = (unsigned char*)smf;
  int t = threadIdx.x;
  int w = t >> 6, lane = t & 63;
  int r = lane & 15, q = lane >> 4;
  int qe = q & 1, qh = q >> 1;
  int a = blockIdx.x >> 4, b0 = (blockIdx.x & 15) * 2;
  int hh = t & 7;

  float m8[8], rs8[8], be8[8];
  if (MODE != 0){
    #pragma unroll
    for (int i=0;i<8;i++){
      int ci = hh*8 + i;
      float S = stats[ci*2], SS = stats[ci*2+1];
      float m = S*(1.f/NTOT);
      m8[i] = m;
      rs8[i] = rsqrtf(SS*(1.f/NTOT) - m*m + 1e-5f) * g[ci];
      be8[i] = be[ci];
    }
  }

  if (MODE == 0){
    #pragma unroll
    for (int c0=0;c0<2;++c0){
      int kb = c0*7, kn = (c0==0)?7:6;
      float4 f0[7], f1[7]; int fl[7];
      #pragma unroll
      for (int k=0;k<7;k++){
        fl[k]=0;
        if (k<kn){
          int idx = t + (kb+k)*256;
          if (idx < 3264){
            int pos = idx>>3;
            int par=pos/136, rem=pos-par*136, pbr=rem/34, pc=rem-pbr*34;
            int pa=a+par, pb=b0+pbr;
            fl[k]=1;
            if (pa>=1&&pa<=32&&pb>=1&&pb<=32&&pc>=1&&pc<=32){
              int nsrc=(pa-1)*1024+(pb-1)*32+(pc-1);
              const float* p = (const float*)src + (size_t)nsrc*64 + hh*8;
              f0[k]=*(const float4*)p; f1[k]=*(const float4*)(p+4);
              fl[k]=2;
            }
          }
        }
      }
      #pragma unroll
      for (int k=0;k<7;k++){
        if (k<kn && fl[k]){
          int pos = (t + (kb+k)*256)>>3;
          uint4 o={0,0,0,0};
          if (fl[k]==2){
            o.x=pk2(f0[k].x,f0[k].y); o.y=pk2(f0[k].z,f0[k].w);
            o.z=pk2(f1[k].x,f1[k].y); o.w=pk2(f1[k].z,f1[k].w);
          }
          *(uint4*)(smb + pos*144 + hh*16) = o;
        }
      }
    }
  } else {
    const int CS = (MODE==2)?5:13;
    const int NC = (MODE==2)?3:1;
    #pragma unroll
    for (int c0=0;c0<NC;++c0){
      int kb = c0*CS;
      int kn = (MODE==2) ? ((c0==2)?3:5) : 13;
      uint4 u[CS]; float4 r0[CS], r1[CS]; int fl[CS];
      #pragma unroll
      for (int k=0;k<CS;k++){
        fl[k]=0;
        if (k<kn){
          int idx = t + (kb+k)*256;
          if (idx < 3264){
            int pos = idx>>3;
            int par=pos/136, rem=pos-par*136, pbr=rem/34, pc=rem-pbr*34;
            int pa=a+par, pb=b0+pbr;
            fl[k]=1;
            if (pa>=1&&pa<=32&&pb>=1&&pb<=32&&pc>=1&&pc<=32){
              int nsrc=(pa-1)*1024+(pb-1)*32+(pc-1);
              u[k] = *(const uint4*)((const unsigned char*)src + ((size_t)nsrc*64 + hh*8)*2);
              if (MODE==2){
                const float* rp = resid + (size_t)nsrc*64 + hh*8;
                r0[k]=*(const float4*)rp; r1[k]=*(const float4*)(rp+4);
              }
              fl[k]=2;
            }
          }
        }
      }
      #pragma unroll
      for (int k=0;k<CS;k++){
        if (k<kn && fl[k]){
          int pos = (t + (kb+k)*256)>>3;
          uint4 o={0,0,0,0};
          if (fl[k]==2){
            float v[8];
            v[0]=bflo(u[k].x); v[1]=bfhi(u[k].x); v[2]=bflo(u[k].y); v[3]=bfhi(u[k].y);
            v[4]=bflo(u[k].z); v[5]=bfhi(u[k].z); v[6]=bflo(u[k].w); v[7]=bfhi(u[k].w);
            float rv[8];
            if (MODE==2){
              rv[0]=r0[k].x; rv[1]=r0[k].y; rv[2]=r0[k].z; rv[3]=r0[k].w;
              rv[4]=r1[k].x; rv[5]=r1[k].y; rv[6]=r1[k].z; rv[7]=r1[k].w;
            }
            #pragma unroll
            for (int i=0;i<8;i++){
              float y = (v[i]-m8[i])*rs8[i] + be8[i];
              if (MODE==2) y += rv[i];
              v[i] = y>0.f ? y : 0.01f*y;
            }
            o.x=pk2(v[0],v[1]); o.y=pk2(v[2],v[3]); o.z=pk2(v[4],v[5]); o.w=pk2(v[6],v[7]);
          }
          *(uint4*)(smb + pos*144 + hh*16) = o;
        }
      }
    }
  }

  int toff[14];
  #pragma unroll
  for (int tp=0;tp<14;++tp){
    int tap = 2*tp + qh;
    int da = tap/9, rem = tap - da*9, db = rem/3, dc = rem - db*3;
    toff[tp] = (tap<27) ? (((da*4+db)*34 + dc)*144) : 0;
  }
  int F[4];
  #pragma unroll
  for (int mt=0;mt<4;mt++) F[mt] = (((mt>>1)*34 + (mt&1)*16 + r)*144) + w*32 + qe*16;
  const unsigned char* wbp = (const unsigned char*)WB + (size_t)w*57344 + lane*16;

  f4v acc[4][4];
  #pragma unroll
  for (int mt=0;mt<4;mt++)
    #pragma unroll
    for (int nt=0;nt<4;nt++){ acc[mt][nt][0]=0.f; acc[mt][nt][1]=0.f; acc[mt][nt][2]=0.f; acc[mt][nt][3]=0.f; }

  __syncthreads();

  s8v aC[4], bC[4], bN[4];
  #pragma unroll
  for (int mt=0;mt<4;mt++) aC[mt] = *(const s8v*)(smb + F[mt] + toff[0]);
  #pragma unroll
  for (int nt=0;nt<4;nt++){ bC[nt] = *(const s8v*)(wbp + nt*1024); bN[nt] = *(const s8v*)(wbp + 4096 + nt*1024); }

  #pragma unroll
  for (int tp=0; tp<14; ++tp){
    s8v aN[4], bN2[4];
    if (tp < 12){
      #pragma unroll
      for (int nt=0;nt<4;nt++) bN2[nt] = *(const s8v*)(wbp + (tp+2)*4096 + nt*1024);
    }
    if (tp < 13){
      #pragma unroll
      for (int mt=0;mt<4;mt++) aN[mt] = *(const s8v*)(smb + F[mt] + toff[tp+1]);
    }
    #pragma unroll
    for (int mt=0;mt<4;mt++)
      #pragma unroll
      for (int nt=0;nt<4;nt++)
        acc[mt][nt] = __builtin_amdgcn_mfma_f32_16x16x32_bf16(aC[mt], bC[nt], acc[mt][nt], 0, 0, 0);
    #pragma unroll
    for (int nt=0;nt<4;nt++) bC[nt] = bN[nt];
    if (tp < 12){
      #pragma unroll
      for (int nt=0;nt<4;nt++) bN[nt] = bN2[nt];
    }
    if (tp < 13){
      #pragma unroll
      for (int mt=0;mt<4;mt++) aC[mt] = aN[mt];
    }
  }

  __syncthreads();
  #pragma unroll
  for (int mt=0;mt<4;mt++)
    #pragma unroll
    for (int nt=0;nt<4;nt++)
      *(float4*)&smf[w*4352 + (nt*16+r)*68 + mt*16 + q*4] = *(float4*)&acc[mt][nt];
  __syncthreads();

  float vals[16];
  {
    int co = t >> 2, pg = t & 3;
    float bv = bias[co];
    #pragma unroll
    for (int i4=0;i4<4;i4++){
      int p = pg*16 + i4*4;
      float4 s0 = *(const float4*)&smf[0*4352 + co*68 + p];
      float4 s1 = *(const float4*)&smf[1*4352 + co*68 + p];
      float4 s2 = *(const float4*)&smf[2*4352 + co*68 + p];
      float4 s3 = *(const float4*)&smf[3*4352 + co*68 + p];
      vals[i4*4+0] = s0.x+s1.x+s2.x+s3.x+bv;
      vals[i4*4+1] = s0.y+s1.y+s2.y+s3.y+bv;
      vals[i4*4+2] = s0.z+s1.z+s2.z+s3.z+bv;
      vals[i4*4+3] = s0.w+s1.w+s2.w+s3.w+bv;
    }
    float s=0.f, ss=0.f;
    #pragma unroll
    for (int i=0;i<16;i++){ s+=vals[i]; ss+=vals[i]*vals[i]; }
    s += __shfl_xor(s,1); ss += __shfl_xor(ss,1);
    s += __shfl_xor(s,2); ss += __shfl_xor(ss,2);
    if (pg==0){
      BNpart[(size_t)blockIdx.x*128 + co*2]     = s;
      BNpart[(size_t)blockIdx.x*128 + co*2 + 1] = ss;
    }
  }
  __syncthreads();
  {
    int co = t >> 2, pg = t & 3;
    #pragma unroll
    for (int i=0;i<16;i++) smf[(pg*16+i)*68 + co] = vals[i];
  }
  __syncthreads();
  {
    int pos = t >> 2, grp = t & 3;
    float v16[16];
    #pragma unroll
    for (int i4=0;i4<4;i4++) *(float4*)&v16[i4*4] = *(const float4*)&smf[pos*68 + grp*16 + i4*4];
    uint4 u0, u1;
    u0.x=pk2(v16[0],v16[1]); u0.y=pk2(v16[2],v16[3]); u0.z=pk2(v16[4],v16[5]); u0.w=pk2(v16[6],v16[7]);
    u1.x=pk2(v16[8],v16[9]); u1.y=pk2(v16[10],v16[11]); u1.z=pk2(v16[12],v16[13]); u1.w=pk2(v16[14],v16[15]);
    int nb = a*1024 + (b0 + (pos>>5))*32 + (pos&31);
    uint4* dst = (uint4*)((unsigned char*)Yout + ((size_t)nb*64 + grp*16)*2);
    dst[0] = u0; dst[1] = u1;
  }
}

// ---------------- reduce 512 BN partials -> 128 consolidated stats ----------------
__global__ __launch_bounds__(1024) void k_bnred(const float* __restrict__ BNpart, float* __restrict__ BNout)
{
  __shared__ float red[8][128];
  int t = threadIdx.x;
  int col = t & 127, grp = t >> 7;
  float acc = 0.f;
  #pragma unroll 8
  for (int r = grp*64; r < grp*64 + 64; ++r) acc += BNpart[r*128 + col];
  red[grp][col] = acc;
  __syncthreads();
  if (grp == 0){
    float s = 0.f;
    #pragma unroll
    for (int g=0; g<8; g++) s += red[g][col];
    BNout[col] = s;
  }
}

// ---------------- fused BN+res chain + 1x1x1 conv + final residual -> fp32 out ----------------
__global__ __launch_bounds__(256) void k_conv1f(const bf16* __restrict__ Y4,
    const float* __restrict__ BN4, const float* __restrict__ g4, const float* __restrict__ be4,
    const bf16* __restrict__ Y2, const float* __restrict__ BN2,
    const float* __restrict__ g2, const float* __restrict__ be2,
    const float* __restrict__ skipf, const float* __restrict__ w8t, const float* __restrict__ b8,
    float* __restrict__ out)
{
  __shared__ float R2[64][68];   // [ci][n]
  __shared__ float skT[64][68];  // [co][n]
  __shared__ float wt[4096];
  __shared__ float bs[64];
  int t = threadIdx.x;
  int n0 = blockIdx.x * 64;
  #pragma unroll
  for (int k=0;k<4;k++){
    int idx = t + k*256;
    *(float4*)&wt[idx*4] = *(const float4*)(w8t + idx*4);
  }
  if (t < 64) bs[t] = b8[t];
  {
    int pos = t >> 2, grp = t & 3;
    int n = n0 + pos;
    float y2[16], y4[16], sk[16];
    load16(Y2 + (size_t)n*64 + grp*16, y2);
    load16(Y4 + (size_t)n*64 + grp*16, y4);
    #pragma unroll
    for (int i4=0;i4<4;i4++) *(float4*)&sk[i4*4] = *(const float4*)(skipf + (size_t)n*64 + grp*16 + i4*4);
    #pragma unroll
    for (int i=0;i<16;i++){
      int ci = grp*16+i;
      float S2=BN2[ci*2], SS2=BN2[ci*2+1];
      float m2=S2*(1.f/NTOT);
      float r2v=rsqrtf(SS2*(1.f/NTOT)-m2*m2+1e-5f);
      float R = (y2[i]-m2)*r2v*g2[ci]+be2[ci] + sk[i];
      R = R>0.f ? R : 0.01f*R;
      float S4=BN4[ci*2], SS4=BN4[ci*2+1];
      float m4=S4*(1.f/NTOT);
      float r4v=rsqrtf(SS4*(1.f/NTOT)-m4*m4+1e-5f);
      float vy = (y4[i]-m4)*r4v*g4[ci]+be4[ci] + R;
      vy = vy>0.f ? vy : 0.01f*vy;
      R2[ci][pos] = vy;
      skT[ci][pos] = sk[i];
    }
  }
  __syncthreads();
  int lane = t & 63, cg = t >> 6;
  float acc[16];
  #pragma unroll
  for (int j=0;j<16;j++) acc[j]=0.f;
  for (int ci=0; ci<64; ci++){
    float rv = R2[ci][lane];
    const float* wr = &wt[ci*64 + cg*16];
    float4 wa = *(const float4*)(wr);
    float4 wb = *(const float4*)(wr+4);
    float4 wc = *(const float4*)(wr+8);
    float4 wd = *(const float4*)(wr+12);
    acc[0]+=rv*wa.x; acc[1]+=rv*wa.y; acc[2]+=rv*wa.z; acc[3]+=rv*wa.w;
    acc[4]+=rv*wb.x; acc[5]+=rv*wb.y; acc[6]+=rv*wb.z; acc[7]+=rv*wb.w;
    acc[8]+=rv*wc.x; acc[9]+=rv*wc.y; acc[10]+=rv*wc.z; acc[11]+=rv*wc.w;
    acc[12]+=rv*wd.x; acc[13]+=rv*wd.y; acc[14]+=rv*wd.z; acc[15]+=rv*wd.w;
  }
  #pragma unroll
  for (int j=0;j<16;j++){
    int co = cg*16+j;
    out[(size_t)co*NTOT + n0 + lane] = acc[j] + bs[co] + skT[co][lane];
  }
}

extern "C" void kernel_launch(void* const* d_in, const int* in_sizes, int n_in,
                              void* d_out, int out_size, void* d_ws, size_t ws_size,
                              hipStream_t stream) {
  (void)in_sizes; (void)n_in; (void)out_size; (void)ws_size;
  const float* x      = (const float*)d_in[0];
  const float* ln_g   = (const float*)d_in[1];
  const float* ln_b   = (const float*)d_in[2];
  const float* gamma  = (const float*)d_in[3];
  const float* qkvv_w = (const float*)d_in[4];
  const float* temp   = (const float*)d_in[5];
  const float* temp2  = (const float*)d_in[6];
  const float* rpb    = (const float*)d_in[7];
  const float* qemb   = (const float*)d_in[8];
  const float* op1w   = (const float*)d_in[9];
  const float* op1b   = (const float*)d_in[10];
  const float* op2w   = (const float*)d_in[11];
  const float* op2b   = (const float*)d_in[12];
  const float* c51_w1 = (const float*)d_in[13];
  const float* c51_b1 = (const float*)d_in[14];
  const float* c51_g1 = (const float*)d_in[15];
  const float* c51_be1= (const float*)d_in[16];
  const float* c51_w2 = (const float*)d_in[17];
  const float* c51_b2 = (const float*)d_in[18];
  const float* c51_g2 = (const float*)d_in[19];
  const float* c51_be2= (const float*)d_in[20];
  const float* c52_w1 = (const float*)d_in[21];
  const float* c52_b1 = (const float*)d_in[22];
  const float* c52_g1 = (const float*)d_in[23];
  const float* c52_be1= (const float*)d_in[24];
  const float* c52_w2 = (const float*)d_in[25];
  const float* c52_b2 = (const float*)d_in[26];
  const float* c52_g2 = (const float*)d_in[27];
  const float* c52_be2= (const float*)d_in[28];
  const float* c8_w   = (const float*)d_in[29];
  const float* c8_b   = (const float*)d_in[30];

  unsigned char* ws = (unsigned char*)d_ws;
  const size_t MB = 1u<<20;
  bf16*  Qh   = (bf16*)(ws + 0);                 // 4 MB [h][N][16]
  bf16*  Kh   = (bf16*)(ws + 4*MB);              // 4 MB
  bf16*  Vsh  = (bf16*)(ws + 8*MB);              // 4 MB
  bf16*  Vch  = (bf16*)(ws + 12*MB);             // 4 MB
  float* skipf= (float*)(ws + 24*MB);            // 8 MB [m][64] fp32
  float* stat = (float*)(ws + 32*MB);
  float* G    = stat + 0;                        // 1024
  float* NQ   = stat + 1024;                     // 64
  float* NK   = stat + 1088;                     // 64
  float* BN1  = stat + 1152;                     // 128 each
  float* BN2  = stat + 1312;
  float* BN3  = stat + 1472;
  float* BN4  = stat + 1632;
  bf16*  WB   = (bf16*)(ws + 33*MB);             // 917504 B
  float* w8t  = (float*)(ws + 33*MB + 1048576);  // 16 KB
  float* BNpart = (float*)(ws + 35*MB);          // 256 KB
  bf16*  Y1   = (bf16*)(ws + 36*MB);             // 4 MB [n][64]
  bf16*  Y2   = (bf16*)(ws + 40*MB);             // 4 MB (persists to conv1f)
  bf16*  Y3   = (bf16*)(ws + 44*MB);             // 4 MB
  bf16*  Y4   = (bf16*)(ws + 48*MB);             // 4 MB -> peak 52 MB

  k_wprep<<<1792,256,0,stream>>>(c51_w1, c51_w2, c52_w1, c52_w2, c8_w, WB, w8t, stat);
  k_qkvv<<<512,256,0,stream>>>(x, ln_g, ln_b, qkvv_w, Qh, Kh, Vsh, Vch);
  k_chanpart<<<dim3(64,4),256,0,stream>>>(Qh, Kh, G, NQ, NK);
  k_spatial<<<512,256,0,stream>>>(Qh, Kh, Vsh, Vch, G, NQ, NK, temp, temp2, rpb, qemb,
                                  x, op1w, op1b, op2w, op2b, gamma, skipf);
  // resblock 1
  k_conv3x<0><<<512,256,0,stream>>>(skipf, nullptr, nullptr, nullptr, nullptr, WB + 0*114688, c51_b1, Y1, BNpart);
  k_bnred<<<1,1024,0,stream>>>(BNpart, BN1);
  k_conv3x<1><<<512,256,0,stream>>>(Y1, BN1, c51_g1, c51_be1, nullptr, WB + 1*114688, c51_b2, Y2, BNpart);
  k_bnred<<<1,1024,0,stream>>>(BNpart, BN2);
  // resblock 2 (staging computes R = lrelu(bn2(Y2)+skip))
  k_conv3x<2><<<512,256,0,stream>>>(Y2, BN2, c51_g2, c51_be2, skipf, WB + 2*114688, c52_b1, Y3, BNpart);
  k_bnred<<<1,1024,0,stream>>>(BNpart, BN3);
  k_conv3x<1><<<512,256,0,stream>>>(Y3, BN3, c52_g1, c52_be1, nullptr, WB + 3*114688, c52_b2, Y4, BNpart);
  k_bnred<<<1,1024,0,stream>>>(BNpart, BN4);
  // final: y = lrelu(bn4(Y4) + R), out = skip + conv1x1(y)
  k_conv1f<<<512,256,0,stream>>>(Y4, BN4, c52_g2, c52_be2, Y2, BN2, c51_g2, c51_be2, skipf, w8t, c8_b, (float*)d_out);
}